// Round 1
// baseline (1536.023 us; speedup 1.0000x reference)
//
#include <hip/hip_runtime.h>
#include <math.h>

#define B_   128
#define L_   128
#define E_   300
#define P_   50
#define FD_  1000
#define FN_  256
#define H2_  100
#define LAB_ 19

// ---- monotonic float<->uint encoding so max-pool can use atomicMax(unsigned) ----
__device__ __forceinline__ unsigned encf(float x) {
    unsigned u = __float_as_uint(x);
    return (u & 0x80000000u) ? ~u : (u | 0x80000000u);
}
__device__ __forceinline__ float decf(unsigned e) {
    unsigned u = (e & 0x80000000u) ? (e ^ 0x80000000u) : ~e;
    return __uint_as_float(u);
}

// enc(-inf) = ~0xFF800000 = 0x007FFFFF
__global__ void init_sf(unsigned* __restrict__ sf_enc) {
    int i = blockIdx.x * 256 + threadIdx.x;
    if (i < B_ * 3 * FN_) sf_enc[i] = 0x007FFFFFu;
}

// ---- build embed[b, i, 0:1000] = [we[b,i], we[b,i+1], we[b,i+2], pos1[p1], pos2[p2]]
// we is the padded embedding lookup: padded idx 0 and L+1 are token 0.
// WF row i==0 is zeroed (word part only).
__global__ __launch_bounds__(256) void build_embed(
    const int* __restrict__ inputs, const int* __restrict__ p1, const int* __restrict__ p2,
    const float* __restrict__ emb, const float* __restrict__ pos1, const float* __restrict__ pos2,
    float* __restrict__ embed)
{
    int bi = blockIdx.x;            // b*L + i
    int b = bi >> 7, i = bi & (L_ - 1);
    int t = threadIdx.x;
    int tok[3];
#pragma unroll
    for (int j = 0; j < 3; ++j) {
        int pi = i + j;             // padded index 0..L+1
        tok[j] = (pi == 0 || pi == L_ + 1) ? 0 : inputs[b * L_ + pi - 1];
    }
    float* dst = embed + (size_t)bi * FD_;
    for (int d = t; d < 3 * E_; d += 256) {
        int j = d / E_, dd = d - j * E_;
        float v = (i == 0) ? 0.f : emb[(size_t)tok[j] * E_ + dd];
        dst[d] = v;
    }
    if (t < 2 * P_) {
        int isp2 = (t >= P_);
        int pp = isp2 ? p2[b * L_ + i] : p1[b * L_ + i];
        const float* ptab = isp2 ? pos2 : pos1;
        int dd = isp2 ? (t - P_) : t;
        dst[3 * E_ + t] = ptab[(size_t)pp * P_ + dd];
    }
}

// ---- tiled transpose: w (FN, K) -> wt (K, FN) ----
__global__ __launch_bounds__(256) void transpose_w(
    const float* __restrict__ w, float* __restrict__ wt, int K)
{
    __shared__ float tile[32][33];
    int kb = blockIdx.x * 32;
    int fb = blockIdx.y * 32;
    int tx = threadIdx.x & 31, ty = threadIdx.x >> 5;   // 32x8
    for (int r = ty; r < 32; r += 8) {
        int kk = kb + tx;
        tile[r][tx] = (kk < K) ? w[(size_t)(fb + r) * K + kk] : 0.f;
    }
    __syncthreads();
    for (int r = ty; r < 32; r += 8) {
        int kk = kb + r;
        if (kk < K) wt[(size_t)kk * FN_ + fb + tx] = tile[tx][r];
    }
}

// ---- span-mean + lexical features straight into o[b, 0:1800] ----
__device__ __forceinline__ int tok_at(const int* inputs, int b, int idx) {
    return (idx >= 0 && idx < L_) ? inputs[b * L_ + idx] : 0;
}
__global__ __launch_bounds__(256) void span_feats(
    const int* __restrict__ inputs,
    const int* __restrict__ e1s, const int* __restrict__ e1e,
    const int* __restrict__ e2s, const int* __restrict__ e2e,
    const float* __restrict__ emb, float* __restrict__ o)
{
    int b = blockIdx.x, t = threadIdx.x;
    int s1 = e1s[b], t1 = e1e[b], s2 = e2s[b], t2 = e2e[b];
    float inv1 = 1.f / (float)(t1 - s1 + 1);
    float inv2 = 1.f / (float)(t2 - s2 + 1);
    float* ob = o + (size_t)b * 1900;
    for (int d = t; d < E_; d += 256) {
        float s = 0.f;
        for (int p = s1; p <= t1; ++p) s += emb[(size_t)tok_at(inputs, b, p) * E_ + d];
        ob[d] = s * inv1;
        s = 0.f;
        for (int p = s2; p <= t2; ++p) s += emb[(size_t)tok_at(inputs, b, p) * E_ + d];
        ob[E_ + d] = s * inv2;
    }
    int ta = tok_at(inputs, b, s1 - 1), tb = tok_at(inputs, b, t1 + 1);
    int tc = tok_at(inputs, b, s2 - 1), td = tok_at(inputs, b, t2 + 1);
    for (int d = t; d < E_; d += 256) {
        ob[2 * E_ + d]  = emb[(size_t)ta * E_ + d];
        ob[3 * E_ + d]  = emb[(size_t)tb * E_ + d];
        ob[4 * E_ + d]  = emb[(size_t)tc * E_ + d];
        ob[5 * E_ + d]  = emb[(size_t)td * E_ + d];
    }
}

// ---- conv-as-GEMM: C[i, f] = sum_c embed[b][i*1000 + c] * wt[c, f],   c < K=k*1000
// fused bias + tanh + max over positions i, atomicMax into sf_enc[b, sfcol + f]
#define BM 64
#define BN 64
#define BK 32
__global__ __launch_bounds__(256) void conv_gemm(
    const float* __restrict__ embed, const float* __restrict__ wt,
    const float* __restrict__ bias, unsigned* __restrict__ sf_enc,
    int K, int M, int sfcol)
{
    int b  = blockIdx.x;
    int i0 = blockIdx.y * BM;
    int n0 = blockIdx.z * BN;
    const float* A = embed + (size_t)b * (L_ * FD_);

    __shared__ float sA[BK][BM + 4];   // transposed A tile, stride 68 (16B-aligned rows)
    __shared__ float sB[BK][BN];
    __shared__ float red[16][BN];

    int t = threadIdx.x;
    int tx = t & 15, ty = t >> 4;
    float acc[4][4] = {};

    int nk = (K + BK - 1) / BK;
    for (int kt = 0; kt < nk; ++kt) {
        int kk0 = kt * BK;
        // A tile: 64 rows x 32 cols = 512 float4
#pragma unroll
        for (int u = 0; u < 2; ++u) {
            int q = t + u * 256;
            int r = q >> 3, col = (q & 7) * 4;
            int i = i0 + r; if (i > M - 1) i = M - 1;     // clamp: masked in epilogue
            int c = kk0 + col;
            float4 v = make_float4(0.f, 0.f, 0.f, 0.f);
            if (c < K) v = *(const float4*)(A + (size_t)i * FD_ + c);
            sA[col + 0][r] = v.x;
            sA[col + 1][r] = v.y;
            sA[col + 2][r] = v.z;
            sA[col + 3][r] = v.w;
        }
        // B tile: 32 rows x 64 cols = 512 float4
#pragma unroll
        for (int u = 0; u < 2; ++u) {
            int q = t + u * 256;
            int r = q >> 4, cg = q & 15;
            int kk = kk0 + r;
            float4 v = make_float4(0.f, 0.f, 0.f, 0.f);
            if (kk < K) v = *(const float4*)(wt + (size_t)kk * FN_ + n0 + cg * 4);
            *(float4*)&sB[r][cg * 4] = v;
        }
        __syncthreads();
#pragma unroll
        for (int kk = 0; kk < BK; ++kk) {
            float4 av = *(const float4*)&sA[kk][ty * 4];
            float4 bv = *(const float4*)&sB[kk][tx * 4];
            float a[4] = {av.x, av.y, av.z, av.w};
            float bb[4] = {bv.x, bv.y, bv.z, bv.w};
#pragma unroll
            for (int mi = 0; mi < 4; ++mi)
#pragma unroll
                for (int ni = 0; ni < 4; ++ni)
                    acc[mi][ni] += a[mi] * bb[ni];
        }
        __syncthreads();
    }

    // epilogue: bias + tanh + max over valid positions
    float bias_v[4];
#pragma unroll
    for (int ni = 0; ni < 4; ++ni) bias_v[ni] = bias[n0 + tx * 4 + ni];
    float cmax[4] = {-INFINITY, -INFINITY, -INFINITY, -INFINITY};
#pragma unroll
    for (int mi = 0; mi < 4; ++mi) {
        int i = i0 + ty * 4 + mi;
        if (i < M) {
#pragma unroll
            for (int ni = 0; ni < 4; ++ni) {
                float v = tanhf(acc[mi][ni] + bias_v[ni]);
                cmax[ni] = fmaxf(cmax[ni], v);
            }
        }
    }
#pragma unroll
    for (int ni = 0; ni < 4; ++ni) red[ty][tx * 4 + ni] = cmax[ni];
    __syncthreads();
    for (int s = 8; s; s >>= 1) {
        if (ty < s) {
#pragma unroll
            for (int ni = 0; ni < 4; ++ni)
                red[ty][tx * 4 + ni] = fmaxf(red[ty][tx * 4 + ni], red[ty + s][tx * 4 + ni]);
        }
        __syncthreads();
    }
    if (ty == 0) {
#pragma unroll
        for (int ni = 0; ni < 4; ++ni)
            atomicMax(&sf_enc[(size_t)b * (3 * FN_) + sfcol + n0 + tx * 4 + ni],
                      encf(red[0][tx * 4 + ni]));
    }
}

// ---- g = tanh(sf @ W1.T + b1) into o[b, 1800:1900] ----
__global__ __launch_bounds__(128) void g_kernel(
    const unsigned* __restrict__ sf_enc, const float* __restrict__ W1,
    const float* __restrict__ b1, float* __restrict__ o)
{
    int b = blockIdx.x, t = threadIdx.x;
    __shared__ float sf[3 * FN_];
    for (int k = t; k < 3 * FN_; k += 128) sf[k] = decf(sf_enc[(size_t)b * (3 * FN_) + k]);
    __syncthreads();
    if (t < H2_) {
        float acc = b1[t];
        for (int k = 0; k < 3 * FN_; ++k) acc += sf[k] * W1[(size_t)t * (3 * FN_) + k];
        o[(size_t)b * 1900 + 1800 + t] = tanhf(acc);
    }
}

// ---- y = o @ W2.T + b2 ----
__global__ __launch_bounds__(256) void final_kernel(
    const float* __restrict__ o, const float* __restrict__ W2,
    const float* __restrict__ b2, float* __restrict__ y)
{
    int b = blockIdx.x;
    int t = threadIdx.x, lane = t & 63, w = t >> 6;
    const float* ob = o + (size_t)b * 1900;
    for (int lab = w; lab < LAB_; lab += 4) {
        float acc = 0.f;
        for (int d = lane; d < 1900; d += 64) acc += ob[d] * W2[(size_t)lab * 1900 + d];
        for (int off = 32; off; off >>= 1) acc += __shfl_down(acc, off);
        if (lane == 0) y[(size_t)b * LAB_ + lab] = acc + b2[lab];
    }
}

extern "C" void kernel_launch(void* const* d_in, const int* in_sizes, int n_in,
                              void* d_out, int out_size, void* d_ws, size_t ws_size,
                              hipStream_t stream) {
    const int*   inputs = (const int*)d_in[0];
    const int*   e1s    = (const int*)d_in[1];
    const int*   e1e    = (const int*)d_in[2];
    const int*   e2s    = (const int*)d_in[3];
    const int*   e2e    = (const int*)d_in[4];
    const int*   p1     = (const int*)d_in[5];
    const int*   p2     = (const int*)d_in[6];
    const float* emb    = (const float*)d_in[7];
    const float* pos1   = (const float*)d_in[8];
    const float* pos2   = (const float*)d_in[9];
    const float* w3     = (const float*)d_in[10];
    const float* cb3    = (const float*)d_in[11];
    const float* w4     = (const float*)d_in[12];
    const float* cb4    = (const float*)d_in[13];
    const float* w5     = (const float*)d_in[14];
    const float* cb5    = (const float*)d_in[15];
    const float* W1     = (const float*)d_in[16];
    const float* b1     = (const float*)d_in[17];
    const float* W2     = (const float*)d_in[18];
    const float* b2     = (const float*)d_in[19];
    float* y = (float*)d_out;

    char* ws = (char*)d_ws;
    size_t off = 0;
    float* embed = (float*)(ws + off); off += (size_t)B_ * L_ * FD_ * 4;     // 65,536,000
    float* wt3   = (float*)(ws + off); off += (size_t)3000 * FN_ * 4;
    float* wt4   = (float*)(ws + off); off += (size_t)4000 * FN_ * 4;
    float* wt5   = (float*)(ws + off); off += (size_t)5000 * FN_ * 4;
    unsigned* sf_enc = (unsigned*)(ws + off); off += (size_t)B_ * 3 * FN_ * 4;
    float* o     = (float*)(ws + off); off += (size_t)B_ * 1900 * 4;

    init_sf<<<dim3((B_ * 3 * FN_ + 255) / 256), dim3(256), 0, stream>>>(sf_enc);
    build_embed<<<dim3(B_ * L_), dim3(256), 0, stream>>>(inputs, p1, p2, emb, pos1, pos2, embed);
    transpose_w<<<dim3((3000 + 31) / 32, FN_ / 32), dim3(256), 0, stream>>>(w3, wt3, 3000);
    transpose_w<<<dim3((4000 + 31) / 32, FN_ / 32), dim3(256), 0, stream>>>(w4, wt4, 4000);
    transpose_w<<<dim3((5000 + 31) / 32, FN_ / 32), dim3(256), 0, stream>>>(w5, wt5, 5000);
    span_feats<<<dim3(B_), dim3(256), 0, stream>>>(inputs, e1s, e1e, e2s, e2e, emb, o);

    conv_gemm<<<dim3(B_, 2, BN == 64 ? 4 : 4), dim3(256), 0, stream>>>(embed, wt3, cb3, sf_enc, 3000, L_ - 3 + 1, 0);
    conv_gemm<<<dim3(B_, 2, 4), dim3(256), 0, stream>>>(embed, wt4, cb4, sf_enc, 4000, L_ - 4 + 1, FN_);
    conv_gemm<<<dim3(B_, 2, 4), dim3(256), 0, stream>>>(embed, wt5, cb5, sf_enc, 5000, L_ - 5 + 1, 2 * FN_);

    g_kernel<<<dim3(B_), dim3(128), 0, stream>>>(sf_enc, W1, b1, o);
    final_kernel<<<dim3(B_), dim3(256), 0, stream>>>(o, W2, b2, y);
}

// Round 2
// 346.396 us; speedup vs baseline: 4.4343x; 4.4343x over previous
//
#include <hip/hip_runtime.h>
#include <math.h>

#define B_   128
#define L_   128
#define E_   300
#define P_   50
#define FD_  1000
#define FN_  256
#define H2_  100
#define LAB_ 19

typedef __attribute__((ext_vector_type(8))) short bf16x8;
typedef __attribute__((ext_vector_type(4))) float f32x4;

// round-to-nearest-even f32 -> bf16
__device__ __forceinline__ unsigned short f2bf(float x) {
    unsigned u = __float_as_uint(x);
    u += 0x7FFFu + ((u >> 16) & 1u);
    return (unsigned short)(u >> 16);
}

__device__ __forceinline__ void gld_lds16(const void* g, void* lds_uniform) {
    __builtin_amdgcn_global_load_lds(
        (const __attribute__((address_space(1))) void*)g,
        (__attribute__((address_space(3))) void*)lds_uniform,
        16, 0, 0);
}

// ---- build embed_bf[b, i, 0:1000] = bf16([we[i], we[i+1], we[i+2], pos1[p1], pos2[p2]])
__global__ __launch_bounds__(256) void build_embed_bf(
    const int* __restrict__ inputs, const int* __restrict__ p1, const int* __restrict__ p2,
    const float* __restrict__ emb, const float* __restrict__ pos1, const float* __restrict__ pos2,
    unsigned short* __restrict__ embed)
{
    int bi = blockIdx.x;            // b*L + i
    int b = bi >> 7, i = bi & (L_ - 1);
    int t = threadIdx.x;
    int tok[3];
#pragma unroll
    for (int j = 0; j < 3; ++j) {
        int pi = i + j;             // padded index 0..L+1
        tok[j] = (pi == 0 || pi == L_ + 1) ? 0 : inputs[b * L_ + pi - 1];
    }
    int pp1 = p1[b * L_ + i], pp2 = p2[b * L_ + i];
    unsigned short* dst = embed + (size_t)bi * FD_;
    for (int d = t; d < FD_; d += 256) {
        float v;
        if (d < 3 * E_) {
            int j = d / E_, dd = d - j * E_;
            v = (i == 0) ? 0.f : emb[(size_t)tok[j] * E_ + dd];
        } else if (d < 3 * E_ + P_) {
            v = pos1[(size_t)pp1 * P_ + (d - 3 * E_)];
        } else {
            v = pos2[(size_t)pp2 * P_ + (d - 3 * E_ - P_)];
        }
        dst[d] = f2bf(v);
    }
}

// ---- convert conv weights (FN, K) f32 -> (FN, Kpad) bf16 with zero pad ----
__global__ __launch_bounds__(256) void convert_w(
    const float* __restrict__ w, unsigned short* __restrict__ out, int K, int Kpad)
{
    int idx = blockIdx.x * 256 + threadIdx.x;
    if (idx >= FN_ * Kpad) return;
    int f = idx / Kpad, c = idx - f * Kpad;
    out[idx] = (c < K) ? f2bf(w[(size_t)f * K + c]) : (unsigned short)0;
}

// ---- span-mean + lexical features straight into o[b, 0:1800] (f32 path) ----
__device__ __forceinline__ int tok_at(const int* inputs, int b, int idx) {
    return (idx >= 0 && idx < L_) ? inputs[b * L_ + idx] : 0;
}
__global__ __launch_bounds__(256) void span_feats(
    const int* __restrict__ inputs,
    const int* __restrict__ e1s, const int* __restrict__ e1e,
    const int* __restrict__ e2s, const int* __restrict__ e2e,
    const float* __restrict__ emb, float* __restrict__ o)
{
    int b = blockIdx.x, t = threadIdx.x;
    int s1 = e1s[b], t1 = e1e[b], s2 = e2s[b], t2 = e2e[b];
    float inv1 = 1.f / (float)(t1 - s1 + 1);
    float inv2 = 1.f / (float)(t2 - s2 + 1);
    float* ob = o + (size_t)b * 1900;
    for (int d = t; d < E_; d += 256) {
        float s = 0.f;
        for (int p = s1; p <= t1; ++p) s += emb[(size_t)tok_at(inputs, b, p) * E_ + d];
        ob[d] = s * inv1;
        s = 0.f;
        for (int p = s2; p <= t2; ++p) s += emb[(size_t)tok_at(inputs, b, p) * E_ + d];
        ob[E_ + d] = s * inv2;
    }
    int ta = tok_at(inputs, b, s1 - 1), tb = tok_at(inputs, b, t1 + 1);
    int tc = tok_at(inputs, b, s2 - 1), td = tok_at(inputs, b, t2 + 1);
    for (int d = t; d < E_; d += 256) {
        ob[2 * E_ + d]  = emb[(size_t)ta * E_ + d];
        ob[3 * E_ + d]  = emb[(size_t)tb * E_ + d];
        ob[4 * E_ + d]  = emb[(size_t)tc * E_ + d];
        ob[5 * E_ + d]  = emb[(size_t)td * E_ + d];
    }
}

// ---- conv as bf16 MFMA GEMM.
// C[i, f] = sum_c A[i*1000 + c] * w[f][c]   (c < Kpad, weights zero-padded)
// block: b = blockIdx.x, n0 = blockIdx.y*64. BM=128 covers all positions ->
// fused max-over-i + bias + tanh, direct store to sf (no atomics).
// 4 waves in 2(m) x 2(n); each wave: 64 rows x 32 cols = acc[4][2] 16x16 frags.
__global__ __launch_bounds__(256) void conv_mfma(
    const unsigned short* __restrict__ embed, const unsigned short* __restrict__ wbf,
    const float* __restrict__ bias, float* __restrict__ sf,
    int Kpad, int M, int sfcol)
{
    __shared__ unsigned short sA[128 * 64];   // [row 0..127][k 0..63], linear
    __shared__ unsigned short sB[64 * 64];    // [f 0..63][k 0..63], linear
    __shared__ float red[2][64];

    int b  = blockIdx.x;
    int n0 = blockIdx.y * 64;
    int t = threadIdx.x;
    int w = t >> 6, lane = t & 63;
    int wm = w & 1, wn = w >> 1;
    int l15 = lane & 15, lhi = lane >> 4;

    const char* Abytes = (const char*)(embed + (size_t)b * (L_ * FD_));
    size_t KpadB = (size_t)Kpad * 2;
    const char* Bbytes = (const char*)wbf + (size_t)n0 * KpadB;

    // staging source geometry: lane covers 16 bytes; 8 lanes per 128B row
    int srow = (w << 3) + (lane >> 3);        // + q*32
    int scol = (lane & 7) << 4;

    f32x4 acc[4][2] = {};
    int nk = Kpad >> 6;

    for (int kt = 0; kt < nk; ++kt) {
        size_t kb = (size_t)kt * 128;         // byte offset along K
        // A tile: 128 rows x 128B = 16KB = 4 rounds of (4 waves x 1KB)
#pragma unroll
        for (int q = 0; q < 4; ++q) {
            int row = srow + q * 32;
            gld_lds16(Abytes + (size_t)row * 2000 + kb + scol,
                      (char*)sA + q * 4096 + w * 1024);
        }
        // B tile: 64 rows x 128B = 8KB = 2 rounds
#pragma unroll
        for (int q = 0; q < 2; ++q) {
            int f = srow + q * 32;
            gld_lds16(Bbytes + (size_t)f * KpadB + kb + scol,
                      (char*)sB + q * 4096 + w * 1024);
        }
        __syncthreads();   // drains vmcnt for global_load_lds

#pragma unroll
        for (int ks = 0; ks < 2; ++ks) {
            int kb8 = ks * 32 + (lhi << 3);
            bf16x8 afr[4], bfr[2];
#pragma unroll
            for (int mf = 0; mf < 4; ++mf) {
                int row = (wm << 6) + (mf << 4) + l15;
                afr[mf] = *(const bf16x8*)&sA[row * 64 + kb8];
            }
#pragma unroll
            for (int nf = 0; nf < 2; ++nf) {
                int fr = (wn << 5) + (nf << 4) + l15;
                bfr[nf] = *(const bf16x8*)&sB[fr * 64 + kb8];
            }
#pragma unroll
            for (int mf = 0; mf < 4; ++mf)
#pragma unroll
                for (int nf = 0; nf < 2; ++nf)
                    acc[mf][nf] = __builtin_amdgcn_mfma_f32_16x16x32_bf16(
                        afr[mf], bfr[nf], acc[mf][nf], 0, 0, 0);
        }
        __syncthreads();
    }

    // epilogue: max over valid positions i < M, then bias + tanh (tanh monotone)
    float bmax[2] = {-INFINITY, -INFINITY};
#pragma unroll
    for (int nf = 0; nf < 2; ++nf) {
#pragma unroll
        for (int mf = 0; mf < 4; ++mf) {
#pragma unroll
            for (int j = 0; j < 4; ++j) {
                int i = (wm << 6) + (mf << 4) + (lhi << 2) + j;
                if (i < M) bmax[nf] = fmaxf(bmax[nf], acc[mf][nf][j]);
            }
        }
        bmax[nf] = fmaxf(bmax[nf], __shfl_xor(bmax[nf], 16));
        bmax[nf] = fmaxf(bmax[nf], __shfl_xor(bmax[nf], 32));
    }
    if (lane < 16) {
        red[wm][(wn << 5) + l15]      = bmax[0];
        red[wm][(wn << 5) + 16 + l15] = bmax[1];
    }
    __syncthreads();
    if (t < 64) {
        float m = fmaxf(red[0][t], red[1][t]);
        sf[(size_t)b * (3 * FN_) + sfcol + n0 + t] = tanhf(m + bias[n0 + t]);
    }
}

// ---- g = tanh(sf @ W1.T + b1) into o[b, 1800:1900] ----
__global__ __launch_bounds__(128) void g_kernel(
    const float* __restrict__ sf, const float* __restrict__ W1,
    const float* __restrict__ b1, float* __restrict__ o)
{
    int b = blockIdx.x, t = threadIdx.x;
    __shared__ float s[3 * FN_];
    for (int k = t; k < 3 * FN_; k += 128) s[k] = sf[(size_t)b * (3 * FN_) + k];
    __syncthreads();
    if (t < H2_) {
        float acc = b1[t];
        const float* wr = W1 + (size_t)t * (3 * FN_);
        for (int k = 0; k < 3 * FN_; ++k) acc += s[k] * wr[k];
        o[(size_t)b * 1900 + 1800 + t] = tanhf(acc);
    }
}

// ---- y = o @ W2.T + b2 ----
__global__ __launch_bounds__(256) void final_kernel(
    const float* __restrict__ o, const float* __restrict__ W2,
    const float* __restrict__ b2, float* __restrict__ y)
{
    int b = blockIdx.x;
    int t = threadIdx.x, lane = t & 63, w = t >> 6;
    const float* ob = o + (size_t)b * 1900;
    for (int lab = w; lab < LAB_; lab += 4) {
        float acc = 0.f;
        for (int d = lane; d < 1900; d += 64) acc += ob[d] * W2[(size_t)lab * 1900 + d];
        for (int off = 32; off; off >>= 1) acc += __shfl_down(acc, off);
        if (lane == 0) y[(size_t)b * LAB_ + lab] = acc + b2[lab];
    }
}

extern "C" void kernel_launch(void* const* d_in, const int* in_sizes, int n_in,
                              void* d_out, int out_size, void* d_ws, size_t ws_size,
                              hipStream_t stream) {
    const int*   inputs = (const int*)d_in[0];
    const int*   e1s    = (const int*)d_in[1];
    const int*   e1e    = (const int*)d_in[2];
    const int*   e2s    = (const int*)d_in[3];
    const int*   e2e    = (const int*)d_in[4];
    const int*   p1     = (const int*)d_in[5];
    const int*   p2     = (const int*)d_in[6];
    const float* emb    = (const float*)d_in[7];
    const float* pos1   = (const float*)d_in[8];
    const float* pos2   = (const float*)d_in[9];
    const float* w3     = (const float*)d_in[10];
    const float* cb3    = (const float*)d_in[11];
    const float* w4     = (const float*)d_in[12];
    const float* cb4    = (const float*)d_in[13];
    const float* w5     = (const float*)d_in[14];
    const float* cb5    = (const float*)d_in[15];
    const float* W1     = (const float*)d_in[16];
    const float* b1     = (const float*)d_in[17];
    const float* W2     = (const float*)d_in[18];
    const float* b2     = (const float*)d_in[19];
    float* y = (float*)d_out;

    const int Kp3 = 3072, Kp4 = 4096, Kp5 = 5056;

    char* ws = (char*)d_ws;
    size_t off = 0;
    unsigned short* embed = (unsigned short*)(ws + off);
    off += (size_t)B_ * L_ * FD_ * 2 + 32768;            // +32KB pad: tail-tile reads beyond end
    unsigned short* wb3 = (unsigned short*)(ws + off); off += (size_t)FN_ * Kp3 * 2;
    unsigned short* wb4 = (unsigned short*)(ws + off); off += (size_t)FN_ * Kp4 * 2;
    unsigned short* wb5 = (unsigned short*)(ws + off); off += (size_t)FN_ * Kp5 * 2;
    float* sf = (float*)(ws + off); off += (size_t)B_ * 3 * FN_ * 4;
    float* o  = (float*)(ws + off); off += (size_t)B_ * 1900 * 4;

    build_embed_bf<<<dim3(B_ * L_), dim3(256), 0, stream>>>(inputs, p1, p2, emb, pos1, pos2, embed);
    convert_w<<<dim3((FN_ * Kp3 + 255) / 256), dim3(256), 0, stream>>>(w3, wb3, 3000, Kp3);
    convert_w<<<dim3((FN_ * Kp4 + 255) / 256), dim3(256), 0, stream>>>(w4, wb4, 4000, Kp4);
    convert_w<<<dim3((FN_ * Kp5 + 255) / 256), dim3(256), 0, stream>>>(w5, wb5, 5000, Kp5);
    span_feats<<<dim3(B_), dim3(256), 0, stream>>>(inputs, e1s, e1e, e2s, e2e, emb, o);

    conv_mfma<<<dim3(B_, FN_ / 64), dim3(256), 0, stream>>>(embed, wb3, cb3, sf, Kp3, L_ - 3 + 1, 0);
    conv_mfma<<<dim3(B_, FN_ / 64), dim3(256), 0, stream>>>(embed, wb4, cb4, sf, Kp4, L_ - 4 + 1, FN_);
    conv_mfma<<<dim3(B_, FN_ / 64), dim3(256), 0, stream>>>(embed, wb5, cb5, sf, Kp5, L_ - 5 + 1, 2 * FN_);

    g_kernel<<<dim3(B_), dim3(128), 0, stream>>>(sf, W1, b1, o);
    final_kernel<<<dim3(B_), dim3(256), 0, stream>>>(o, W2, b2, y);
}

// Round 3
// 270.120 us; speedup vs baseline: 5.6865x; 1.2824x over previous
//
#include <hip/hip_runtime.h>
#include <math.h>

#define B_   128
#define L_   128
#define E_   300
#define P_   50
#define FD_  1000
#define FN_  256
#define H2_  100
#define LAB_ 19

typedef __attribute__((ext_vector_type(8))) short bf16x8;
typedef __attribute__((ext_vector_type(4))) float f32x4;

// round-to-nearest-even f32 -> bf16
__device__ __forceinline__ unsigned short f2bf(float x) {
    unsigned u = __float_as_uint(x);
    u += 0x7FFFu + ((u >> 16) & 1u);
    return (unsigned short)(u >> 16);
}

__device__ __forceinline__ void gld_lds16(const void* g, void* lds_uniform) {
    __builtin_amdgcn_global_load_lds(
        (const __attribute__((address_space(1))) void*)g,
        (__attribute__((address_space(3))) void*)lds_uniform,
        16, 0, 0);
}

// ---- zero the tail pad after embed so K-padding tail reads are finite zeros ----
__global__ __launch_bounds__(256) void zero_pad(unsigned short* __restrict__ padstart, int n) {
    int i = blockIdx.x * 256 + threadIdx.x;
    if (i < n) padstart[i] = 0;
}

// ---- build embed_bf[b, i, 0:1000] = bf16([we[i], we[i+1], we[i+2], pos1[p1], pos2[p2]])
__global__ __launch_bounds__(256) void build_embed_bf(
    const int* __restrict__ inputs, const int* __restrict__ p1, const int* __restrict__ p2,
    const float* __restrict__ emb, const float* __restrict__ pos1, const float* __restrict__ pos2,
    unsigned short* __restrict__ embed)
{
    int bi = blockIdx.x;            // b*L + i
    int b = bi >> 7, i = bi & (L_ - 1);
    int t = threadIdx.x;
    int tok[3];
#pragma unroll
    for (int j = 0; j < 3; ++j) {
        int pi = i + j;             // padded index 0..L+1
        tok[j] = (pi == 0 || pi == L_ + 1) ? 0 : inputs[b * L_ + pi - 1];
    }
    int pp1 = p1[b * L_ + i], pp2 = p2[b * L_ + i];
    unsigned short* dst = embed + (size_t)bi * FD_;
    for (int d = t; d < FD_; d += 256) {
        float v;
        if (d < 3 * E_) {
            int j = d / E_, dd = d - j * E_;
            v = (i == 0) ? 0.f : emb[(size_t)tok[j] * E_ + dd];
        } else if (d < 3 * E_ + P_) {
            v = pos1[(size_t)pp1 * P_ + (d - 3 * E_)];
        } else {
            v = pos2[(size_t)pp2 * P_ + (d - 3 * E_ - P_)];
        }
        dst[d] = f2bf(v);
    }
}

// ---- convert conv weights (FN, K) f32 -> (FN, Kpad) bf16 with zero pad ----
__global__ __launch_bounds__(256) void convert_w(
    const float* __restrict__ w, unsigned short* __restrict__ out, int K, int Kpad)
{
    int idx = blockIdx.x * 256 + threadIdx.x;
    if (idx >= FN_ * Kpad) return;
    int f = idx / Kpad, c = idx - f * Kpad;
    out[idx] = (c < K) ? f2bf(w[(size_t)f * K + c]) : (unsigned short)0;
}

// ---- span-mean + lexical features straight into o[b, 0:1800] (f32 path) ----
__device__ __forceinline__ int tok_at(const int* inputs, int b, int idx) {
    return (idx >= 0 && idx < L_) ? inputs[b * L_ + idx] : 0;
}
__global__ __launch_bounds__(256) void span_feats(
    const int* __restrict__ inputs,
    const int* __restrict__ e1s, const int* __restrict__ e1e,
    const int* __restrict__ e2s, const int* __restrict__ e2e,
    const float* __restrict__ emb, float* __restrict__ o)
{
    int b = blockIdx.x, t = threadIdx.x;
    int s1 = e1s[b], t1 = e1e[b], s2 = e2s[b], t2 = e2e[b];
    float inv1 = 1.f / (float)(t1 - s1 + 1);
    float inv2 = 1.f / (float)(t2 - s2 + 1);
    float* ob = o + (size_t)b * 1900;
    for (int d = t; d < E_; d += 256) {
        float s = 0.f;
        for (int p = s1; p <= t1; ++p) s += emb[(size_t)tok_at(inputs, b, p) * E_ + d];
        ob[d] = s * inv1;
        s = 0.f;
        for (int p = s2; p <= t2; ++p) s += emb[(size_t)tok_at(inputs, b, p) * E_ + d];
        ob[E_ + d] = s * inv2;
    }
    int ta = tok_at(inputs, b, s1 - 1), tb = tok_at(inputs, b, t1 + 1);
    int tc = tok_at(inputs, b, s2 - 1), td = tok_at(inputs, b, t2 + 1);
    for (int d = t; d < E_; d += 256) {
        ob[2 * E_ + d]  = emb[(size_t)ta * E_ + d];
        ob[3 * E_ + d]  = emb[(size_t)tb * E_ + d];
        ob[4 * E_ + d]  = emb[(size_t)tc * E_ + d];
        ob[5 * E_ + d]  = emb[(size_t)td * E_ + d];
    }
}

// ---- fused conv-as-GEMM for all three filter sizes.
// grid = (b, conv, ntile). Block: 256 threads, 4 waves in 2(m) x 2(n),
// tile BM=128 (all positions) x BN=128 x BK=64. XOR-swizzled LDS (T2 via
// pre-swizzled global source, rule #21). Fused max-over-i + bias + tanh.
__global__ __launch_bounds__(256) void conv_mfma_fused(
    const unsigned short* __restrict__ embed,
    const unsigned short* __restrict__ wb3, const unsigned short* __restrict__ wb4,
    const unsigned short* __restrict__ wb5,
    const float* __restrict__ cb3, const float* __restrict__ cb4, const float* __restrict__ cb5,
    float* __restrict__ sf)
{
    __shared__ unsigned short sA[128 * 64];   // [row 0..127][64 k-shorts], chunk-swizzled
    __shared__ unsigned short sB[128 * 64];   // [f 0..127][64 k-shorts], chunk-swizzled
    __shared__ float red[2][128];

    int b    = blockIdx.x;
    int conv = blockIdx.y;                    // 0,1,2 -> k=3,4,5
    int n0   = blockIdx.z << 7;               // 0 or 128

    const unsigned short* wbf = (conv == 0) ? wb3 : (conv == 1) ? wb4 : wb5;
    const float* bias         = (conv == 0) ? cb3 : (conv == 1) ? cb4 : cb5;
    int Kpad  = (conv == 0) ? 3072 : (conv == 1) ? 4096 : 5056;
    int M     = 126 - conv;                   // L - k + 1
    int sfcol = conv << 8;                    // conv * FN

    int t = threadIdx.x;
    int w = t >> 6, lane = t & 63;
    int wm = w & 1, wn = w >> 1;
    int l15 = lane & 15, lhi = lane >> 4;

    const char* Abytes = (const char*)(embed + (size_t)b * (L_ * FD_));
    size_t KpadB = (size_t)Kpad * 2;
    const char* Bbytes = (const char*)wbf + (size_t)n0 * KpadB;

    // staging geometry: lane -> LDS dest byte q*4096 + w*1024 + lane*16
    //   row = q*32 + r_base, physical chunk p = lane&7 (16B chunks, 8 per row)
    //   source chunk d = p ^ (row&7)  (q*32 doesn't change row&7)
    int r_base = (w << 3) + (lane >> 3);
    int dchunk = (lane & 7) ^ (r_base & 7);
    size_t soff = (size_t)dchunk << 4;

    f32x4 acc[4][4] = {};
    int nk = Kpad >> 6;

    for (int kt = 0; kt < nk; ++kt) {
        size_t kb = (size_t)kt << 7;          // 128 bytes of K per tile
#pragma unroll
        for (int q = 0; q < 4; ++q) {
            int row = r_base + (q << 5);
            gld_lds16(Abytes + (size_t)row * 2000 + kb + soff,
                      (char*)sA + (q << 12) + (w << 10));
            gld_lds16(Bbytes + (size_t)row * KpadB + kb + soff,
                      (char*)sB + (q << 12) + (w << 10));
        }
        __syncthreads();

#pragma unroll
        for (int ks = 0; ks < 2; ++ks) {
            int c = (ks << 2) + lhi;          // logical chunk 0..7
            bf16x8 afr[4], bfr[4];
#pragma unroll
            for (int mf = 0; mf < 4; ++mf) {
                int row = (wm << 6) + (mf << 4) + l15;
                int pc = c ^ (row & 7);
                afr[mf] = *(const bf16x8*)&sA[row * 64 + pc * 8];
            }
#pragma unroll
            for (int nf = 0; nf < 4; ++nf) {
                int fr = (wn << 6) + (nf << 4) + l15;
                int pc = c ^ (fr & 7);
                bfr[nf] = *(const bf16x8*)&sB[fr * 64 + pc * 8];
            }
#pragma unroll
            for (int mf = 0; mf < 4; ++mf)
#pragma unroll
                for (int nf = 0; nf < 4; ++nf)
                    acc[mf][nf] = __builtin_amdgcn_mfma_f32_16x16x32_bf16(
                        afr[mf], bfr[nf], acc[mf][nf], 0, 0, 0);
        }
        __syncthreads();
    }

    // epilogue: max over valid positions i < M (tanh monotone -> pool first)
#pragma unroll
    for (int nf = 0; nf < 4; ++nf) {
        float bmax = -INFINITY;
#pragma unroll
        for (int mf = 0; mf < 4; ++mf) {
#pragma unroll
            for (int j = 0; j < 4; ++j) {
                int i = (wm << 6) + (mf << 4) + (lhi << 2) + j;
                if (i < M) bmax = fmaxf(bmax, acc[mf][nf][j]);
            }
        }
        bmax = fmaxf(bmax, __shfl_xor(bmax, 16));
        bmax = fmaxf(bmax, __shfl_xor(bmax, 32));
        if (lane < 16) red[wm][(wn << 6) + (nf << 4) + l15] = bmax;
    }
    __syncthreads();
    if (t < 128) {
        float m = fmaxf(red[0][t], red[1][t]);
        sf[(size_t)b * (3 * FN_) + sfcol + n0 + t] = tanhf(m + bias[n0 + t]);
    }
}

// ---- g = tanh(sf @ W1.T + b1) into o[b, 1800:1900] ----
__global__ __launch_bounds__(128) void g_kernel(
    const float* __restrict__ sf, const float* __restrict__ W1,
    const float* __restrict__ b1, float* __restrict__ o)
{
    int b = blockIdx.x, t = threadIdx.x;
    __shared__ float s[3 * FN_];
    for (int k = t; k < 3 * FN_; k += 128) s[k] = sf[(size_t)b * (3 * FN_) + k];
    __syncthreads();
    if (t < H2_) {
        float acc = b1[t];
        const float* wr = W1 + (size_t)t * (3 * FN_);
        for (int k = 0; k < 3 * FN_; ++k) acc += s[k] * wr[k];
        o[(size_t)b * 1900 + 1800 + t] = tanhf(acc);
    }
}

// ---- y = o @ W2.T + b2 ----
__global__ __launch_bounds__(256) void final_kernel(
    const float* __restrict__ o, const float* __restrict__ W2,
    const float* __restrict__ b2, float* __restrict__ y)
{
    int b = blockIdx.x;
    int t = threadIdx.x, lane = t & 63, w = t >> 6;
    const float* ob = o + (size_t)b * 1900;
    for (int lab = w; lab < LAB_; lab += 4) {
        float acc = 0.f;
        for (int d = lane; d < 1900; d += 64) acc += ob[d] * W2[(size_t)lab * 1900 + d];
        for (int off = 32; off; off >>= 1) acc += __shfl_down(acc, off);
        if (lane == 0) y[(size_t)b * LAB_ + lab] = acc + b2[lab];
    }
}

extern "C" void kernel_launch(void* const* d_in, const int* in_sizes, int n_in,
                              void* d_out, int out_size, void* d_ws, size_t ws_size,
                              hipStream_t stream) {
    const int*   inputs = (const int*)d_in[0];
    const int*   e1s    = (const int*)d_in[1];
    const int*   e1e    = (const int*)d_in[2];
    const int*   e2s    = (const int*)d_in[3];
    const int*   e2e    = (const int*)d_in[4];
    const int*   p1     = (const int*)d_in[5];
    const int*   p2     = (const int*)d_in[6];
    const float* emb    = (const float*)d_in[7];
    const float* pos1   = (const float*)d_in[8];
    const float* pos2   = (const float*)d_in[9];
    const float* w3     = (const float*)d_in[10];
    const float* cb3    = (const float*)d_in[11];
    const float* w4     = (const float*)d_in[12];
    const float* cb4    = (const float*)d_in[13];
    const float* w5     = (const float*)d_in[14];
    const float* cb5    = (const float*)d_in[15];
    const float* W1     = (const float*)d_in[16];
    const float* b1     = (const float*)d_in[17];
    const float* W2     = (const float*)d_in[18];
    const float* b2     = (const float*)d_in[19];
    float* y = (float*)d_out;

    const int Kp3 = 3072, Kp4 = 4096, Kp5 = 5056;
    const int PAD_ELEMS = 16384;                          // 32KB zero tail after embed

    char* ws = (char*)d_ws;
    size_t off = 0;
    unsigned short* embed = (unsigned short*)(ws + off);
    off += (size_t)B_ * L_ * FD_ * 2 + PAD_ELEMS * 2;
    unsigned short* wb3 = (unsigned short*)(ws + off); off += (size_t)FN_ * Kp3 * 2;
    unsigned short* wb4 = (unsigned short*)(ws + off); off += (size_t)FN_ * Kp4 * 2;
    unsigned short* wb5 = (unsigned short*)(ws + off); off += (size_t)FN_ * Kp5 * 2;
    float* sf = (float*)(ws + off); off += (size_t)B_ * 3 * FN_ * 4;
    float* o  = (float*)(ws + off); off += (size_t)B_ * 1900 * 4;

    zero_pad<<<dim3((PAD_ELEMS + 255) / 256), dim3(256), 0, stream>>>(
        embed + (size_t)B_ * L_ * FD_, PAD_ELEMS);
    build_embed_bf<<<dim3(B_ * L_), dim3(256), 0, stream>>>(inputs, p1, p2, emb, pos1, pos2, embed);
    convert_w<<<dim3((FN_ * Kp3 + 255) / 256), dim3(256), 0, stream>>>(w3, wb3, 3000, Kp3);
    convert_w<<<dim3((FN_ * Kp4 + 255) / 256), dim3(256), 0, stream>>>(w4, wb4, 4000, Kp4);
    convert_w<<<dim3((FN_ * Kp5 + 255) / 256), dim3(256), 0, stream>>>(w5, wb5, 5000, Kp5);
    span_feats<<<dim3(B_), dim3(256), 0, stream>>>(inputs, e1s, e1e, e2s, e2e, emb, o);

    conv_mfma_fused<<<dim3(B_, 3, 2), dim3(256), 0, stream>>>(
        embed, wb3, wb4, wb5, cb3, cb4, cb5, sf);

    g_kernel<<<dim3(B_), dim3(128), 0, stream>>>(sf, W1, b1, o);
    final_kernel<<<dim3(B_), dim3(256), 0, stream>>>(o, W2, b2, y);
}

// Round 4
// 261.924 us; speedup vs baseline: 5.8644x; 1.0313x over previous
//
#include <hip/hip_runtime.h>
#include <math.h>

#define B_   128
#define L_   128
#define E_   300
#define P_   50
#define FD_  1000
#define FN_  256
#define H2_  100
#define LAB_ 19

#define KP3 3072
#define KP4 4096
#define KP5 5056
#define PAD_ELEMS 16384

typedef __attribute__((ext_vector_type(8))) short bf16x8;
typedef __attribute__((ext_vector_type(4))) float f32x4;

// round-to-nearest-even f32 -> bf16
__device__ __forceinline__ unsigned short f2bf(float x) {
    unsigned u = __float_as_uint(x);
    u += 0x7FFFu + ((u >> 16) & 1u);
    return (unsigned short)(u >> 16);
}

__device__ __forceinline__ void gld_lds16(const void* g, void* lds_uniform) {
    __builtin_amdgcn_global_load_lds(
        (const __attribute__((address_space(1))) void*)g,
        (__attribute__((address_space(3))) void*)lds_uniform,
        16, 0, 0);
}

#define MEMFENCE asm volatile("" ::: "memory")

// ---- build embed_bf[b, i, 0:1000] = bf16([we[i], we[i+1], we[i+2], pos1[p1], pos2[p2]])
__global__ __launch_bounds__(256) void build_embed_bf(
    const int* __restrict__ inputs, const int* __restrict__ p1, const int* __restrict__ p2,
    const float* __restrict__ emb, const float* __restrict__ pos1, const float* __restrict__ pos2,
    unsigned short* __restrict__ embed)
{
    int bi = blockIdx.x;            // b*L + i
    int b = bi >> 7, i = bi & (L_ - 1);
    int t = threadIdx.x;
    int tok[3];
#pragma unroll
    for (int j = 0; j < 3; ++j) {
        int pi = i + j;             // padded index 0..L+1
        tok[j] = (pi == 0 || pi == L_ + 1) ? 0 : inputs[b * L_ + pi - 1];
    }
    int pp1 = p1[b * L_ + i], pp2 = p2[b * L_ + i];
    unsigned short* dst = embed + (size_t)bi * FD_;
    for (int d = t; d < FD_; d += 256) {
        float v;
        if (d < 3 * E_) {
            int j = d / E_, dd = d - j * E_;
            v = (i == 0) ? 0.f : emb[(size_t)tok[j] * E_ + dd];
        } else if (d < 3 * E_ + P_) {
            v = pos1[(size_t)pp1 * P_ + (d - 3 * E_)];
        } else {
            v = pos2[(size_t)pp2 * P_ + (d - 3 * E_ - P_)];
        }
        dst[d] = f2bf(v);
    }
}

// ---- prep: convert all 3 conv weights (FN,K)f32 -> (FN,Kpad)bf16 + zero embed tail pad ----
__global__ __launch_bounds__(256) void prep_kernel(
    const float* __restrict__ w3, const float* __restrict__ w4, const float* __restrict__ w5,
    unsigned short* __restrict__ wb3, unsigned short* __restrict__ wb4,
    unsigned short* __restrict__ wb5, unsigned short* __restrict__ pad)
{
    const int n3 = FN_ * KP3, n4 = FN_ * KP4, n5 = FN_ * KP5;
    int idx = blockIdx.x * 256 + threadIdx.x;
    if (idx < n3) {
        int f = idx / KP3, c = idx - f * KP3;
        wb3[idx] = (c < 3000) ? f2bf(w3[(size_t)f * 3000 + c]) : (unsigned short)0;
    } else if ((idx -= n3) < n4) {
        int f = idx / KP4, c = idx - f * KP4;
        wb4[idx] = (c < 4000) ? f2bf(w4[(size_t)f * 4000 + c]) : (unsigned short)0;
    } else if ((idx -= n4) < n5) {
        int f = idx / KP5, c = idx - f * KP5;
        wb5[idx] = (c < 5000) ? f2bf(w5[(size_t)f * 5000 + c]) : (unsigned short)0;
    } else if ((idx -= n5) < PAD_ELEMS) {
        pad[idx] = 0;
    }
}

// ---- fused conv-as-GEMM, 2-phase double-buffered pipeline (T3-minimum + T4 counted vmcnt).
// grid = (3, b, ntile), conv = 2 - blockIdx.x (longest first). 4 waves 2(m)x2(n),
// tile BM=128 x BN=128 x BK=64, XOR-swizzled LDS via pre-swizzled global source.
__global__ __launch_bounds__(256) void conv_mfma_fused(
    const unsigned short* __restrict__ embed,
    const unsigned short* __restrict__ wb3, const unsigned short* __restrict__ wb4,
    const unsigned short* __restrict__ wb5,
    const float* __restrict__ cb3, const float* __restrict__ cb4, const float* __restrict__ cb5,
    float* __restrict__ sf)
{
    __shared__ unsigned short sA[2][128 * 64];   // 2 x 16 KB, chunk-swizzled
    __shared__ unsigned short sB[2][128 * 64];   // 2 x 16 KB
    __shared__ float red[2][128];

    int conv = 2 - blockIdx.x;                // 2,1,0 -> k=5,4,3 (longest dispatched first)
    int b    = blockIdx.y;
    int n0   = blockIdx.z << 7;               // 0 or 128

    const unsigned short* wbf = (conv == 0) ? wb3 : (conv == 1) ? wb4 : wb5;
    const float* bias         = (conv == 0) ? cb3 : (conv == 1) ? cb4 : cb5;
    int Kpad  = (conv == 0) ? KP3 : (conv == 1) ? KP4 : KP5;
    int M     = 126 - conv;                   // L - k + 1
    int sfcol = conv << 8;                    // conv * FN

    int t = threadIdx.x;
    int w = t >> 6, lane = t & 63;
    int wm = w & 1, wn = w >> 1;
    int l15 = lane & 15, lhi = lane >> 4;

    const char* Abytes = (const char*)(embed + (size_t)b * (L_ * FD_));
    size_t KpadB = (size_t)Kpad * 2;
    const char* Bbytes = (const char*)wbf + (size_t)n0 * KpadB;

    // staging: LDS dest is linear (buf, q*4096 + w*1024 + lane*16);
    // global source chunk pre-swizzled: d = (lane&7) ^ (row&7)  [involution]
    int r_base = (w << 3) + (lane >> 3);
    int dchunk = (lane & 7) ^ (r_base & 7);
    size_t soff = (size_t)dchunk << 4;
    char* sAd = (char*)sA + (w << 10);
    char* sBd = (char*)sB + (w << 10);

    f32x4 acc[4][4] = {};
    int nk = Kpad >> 6;

#define STAGE(BUF, KT)                                                          \
    {                                                                           \
        size_t kb = (size_t)(KT) << 7;                                          \
        _Pragma("unroll")                                                       \
        for (int q = 0; q < 4; ++q) {                                           \
            int row = r_base + (q << 5);                                        \
            gld_lds16(Abytes + (size_t)row * 2000 + kb + soff,                  \
                      sAd + (size_t)(BUF) * 16384 + (q << 12));                 \
            gld_lds16(Bbytes + (size_t)row * KpadB + kb + soff,                 \
                      sBd + (size_t)(BUF) * 16384 + (q << 12));                 \
        }                                                                       \
    }

    STAGE(0, 0);
    int cur = 0;
    for (int kt = 0; kt < nk; ++kt) {
        if (kt + 1 < nk) {
            STAGE(cur ^ 1, kt + 1);
            asm volatile("s_waitcnt vmcnt(8)" ::: "memory");   // cur's 8 loads landed; next's in flight
        } else {
            asm volatile("s_waitcnt vmcnt(0)" ::: "memory");
        }
        MEMFENCE; __builtin_amdgcn_s_barrier(); MEMFENCE;

        const unsigned short* cA = sA[cur];
        const unsigned short* cB = sB[cur];
#pragma unroll
        for (int ks = 0; ks < 2; ++ks) {
            int c = (ks << 2) + lhi;          // logical 16B chunk 0..7
            bf16x8 afr[4], bfr[4];
#pragma unroll
            for (int mf = 0; mf < 4; ++mf) {
                int row = (wm << 6) + (mf << 4) + l15;
                int pc = c ^ (row & 7);
                afr[mf] = *(const bf16x8*)&cA[row * 64 + pc * 8];
            }
#pragma unroll
            for (int nf = 0; nf < 4; ++nf) {
                int fr = (wn << 6) + (nf << 4) + l15;
                int pc = c ^ (fr & 7);
                bfr[nf] = *(const bf16x8*)&cB[fr * 64 + pc * 8];
            }
#pragma unroll
            for (int mf = 0; mf < 4; ++mf)
#pragma unroll
                for (int nf = 0; nf < 4; ++nf)
                    acc[mf][nf] = __builtin_amdgcn_mfma_f32_16x16x32_bf16(
                        afr[mf], bfr[nf], acc[mf][nf], 0, 0, 0);
        }
        MEMFENCE; __builtin_amdgcn_s_barrier(); MEMFENCE;   // all waves done reading cur
        cur ^= 1;
    }
#undef STAGE

    // epilogue: max over valid positions i < M (tanh monotone -> pool before tanh)
#pragma unroll
    for (int nf = 0; nf < 4; ++nf) {
        float bmax = -INFINITY;
#pragma unroll
        for (int mf = 0; mf < 4; ++mf) {
#pragma unroll
            for (int j = 0; j < 4; ++j) {
                int i = (wm << 6) + (mf << 4) + (lhi << 2) + j;
                if (i < M) bmax = fmaxf(bmax, acc[mf][nf][j]);
            }
        }
        bmax = fmaxf(bmax, __shfl_xor(bmax, 16));
        bmax = fmaxf(bmax, __shfl_xor(bmax, 32));
        if (lane < 16) red[wm][(wn << 6) + (nf << 4) + l15] = bmax;
    }
    __syncthreads();
    if (t < 128) {
        float m = fmaxf(red[0][t], red[1][t]);
        sf[(size_t)b * (3 * FN_) + sfcol + n0 + t] = tanhf(m + bias[n0 + t]);
    }
}

// ---- tail: span/lex feats + g + final logits, one block per b ----
__device__ __forceinline__ int tok_at(const int* inputs, int b, int idx) {
    return (idx >= 0 && idx < L_) ? inputs[b * L_ + idx] : 0;
}
__global__ __launch_bounds__(256) void tail_kernel(
    const int* __restrict__ inputs,
    const int* __restrict__ e1s, const int* __restrict__ e1e,
    const int* __restrict__ e2s, const int* __restrict__ e2e,
    const float* __restrict__ emb, const float* __restrict__ sf,
    const float* __restrict__ W1, const float* __restrict__ b1,
    const float* __restrict__ W2, const float* __restrict__ b2,
    float* __restrict__ y)
{
    __shared__ float o_loc[1900];
    __shared__ float sfl[3 * FN_];

    int b = blockIdx.x, t = threadIdx.x;
    int lane = t & 63, w = t >> 6;

    for (int k = t; k < 3 * FN_; k += 256) sfl[k] = sf[(size_t)b * (3 * FN_) + k];

    int s1 = e1s[b], t1 = e1e[b], s2 = e2s[b], t2 = e2e[b];
    float inv1 = 1.f / (float)(t1 - s1 + 1);
    float inv2 = 1.f / (float)(t2 - s2 + 1);
    int ta = tok_at(inputs, b, s1 - 1), tb = tok_at(inputs, b, t1 + 1);
    int tc = tok_at(inputs, b, s2 - 1), td = tok_at(inputs, b, t2 + 1);
    for (int d = t; d < E_; d += 256) {
        float s = 0.f;
        for (int p = s1; p <= t1; ++p) s += emb[(size_t)tok_at(inputs, b, p) * E_ + d];
        o_loc[d] = s * inv1;
        s = 0.f;
        for (int p = s2; p <= t2; ++p) s += emb[(size_t)tok_at(inputs, b, p) * E_ + d];
        o_loc[E_ + d] = s * inv2;
        o_loc[2 * E_ + d] = emb[(size_t)ta * E_ + d];
        o_loc[3 * E_ + d] = emb[(size_t)tb * E_ + d];
        o_loc[4 * E_ + d] = emb[(size_t)tc * E_ + d];
        o_loc[5 * E_ + d] = emb[(size_t)td * E_ + d];
    }
    __syncthreads();

    // g: warp-parallel dots over 768 (coalesced W1 reads)
    for (int h = w; h < H2_; h += 4) {
        const float* wr = W1 + (size_t)h * (3 * FN_);
        float acc = 0.f;
#pragma unroll
        for (int j = 0; j < 12; ++j) acc += sfl[lane + (j << 6)] * wr[lane + (j << 6)];
        for (int off = 32; off; off >>= 1) acc += __shfl_down(acc, off);
        if (lane == 0) o_loc[1800 + h] = tanhf(acc + b1[h]);
    }
    __syncthreads();

    // y = o_loc @ W2.T + b2
    for (int lab = w; lab < LAB_; lab += 4) {
        const float* wr = W2 + (size_t)lab * 1900;
        float acc = 0.f;
        for (int d = lane; d < 1900; d += 64) acc += o_loc[d] * wr[d];
        for (int off = 32; off; off >>= 1) acc += __shfl_down(acc, off);
        if (lane == 0) y[(size_t)b * LAB_ + lab] = acc + b2[lab];
    }
}

extern "C" void kernel_launch(void* const* d_in, const int* in_sizes, int n_in,
                              void* d_out, int out_size, void* d_ws, size_t ws_size,
                              hipStream_t stream) {
    const int*   inputs = (const int*)d_in[0];
    const int*   e1s    = (const int*)d_in[1];
    const int*   e1e    = (const int*)d_in[2];
    const int*   e2s    = (const int*)d_in[3];
    const int*   e2e    = (const int*)d_in[4];
    const int*   p1     = (const int*)d_in[5];
    const int*   p2     = (const int*)d_in[6];
    const float* emb    = (const float*)d_in[7];
    const float* pos1   = (const float*)d_in[8];
    const float* pos2   = (const float*)d_in[9];
    const float* w3     = (const float*)d_in[10];
    const float* cb3    = (const float*)d_in[11];
    const float* w4     = (const float*)d_in[12];
    const float* cb4    = (const float*)d_in[13];
    const float* w5     = (const float*)d_in[14];
    const float* cb5    = (const float*)d_in[15];
    const float* W1     = (const float*)d_in[16];
    const float* b1     = (const float*)d_in[17];
    const float* W2     = (const float*)d_in[18];
    const float* b2     = (const float*)d_in[19];
    float* y = (float*)d_out;

    char* ws = (char*)d_ws;
    size_t off = 0;
    unsigned short* embed = (unsigned short*)(ws + off);
    off += (size_t)B_ * L_ * FD_ * 2 + (size_t)PAD_ELEMS * 2;
    unsigned short* wb3 = (unsigned short*)(ws + off); off += (size_t)FN_ * KP3 * 2;
    unsigned short* wb4 = (unsigned short*)(ws + off); off += (size_t)FN_ * KP4 * 2;
    unsigned short* wb5 = (unsigned short*)(ws + off); off += (size_t)FN_ * KP5 * 2;
    float* sf = (float*)(ws + off); off += (size_t)B_ * 3 * FN_ * 4;

    const int prep_total = FN_ * (KP3 + KP4 + KP5) + PAD_ELEMS;
    prep_kernel<<<dim3((prep_total + 255) / 256), dim3(256), 0, stream>>>(
        w3, w4, w5, wb3, wb4, wb5, embed + (size_t)B_ * L_ * FD_);
    build_embed_bf<<<dim3(B_ * L_), dim3(256), 0, stream>>>(inputs, p1, p2, emb, pos1, pos2, embed);

    conv_mfma_fused<<<dim3(3, B_, 2), dim3(256), 0, stream>>>(
        embed, wb3, wb4, wb5, cb3, cb4, cb5, sf);

    tail_kernel<<<dim3(B_), dim3(256), 0, stream>>>(
        inputs, e1s, e1e, e2s, e2e, emb, sf, W1, b1, W2, b2, y);
}

// Round 5
// 224.548 us; speedup vs baseline: 6.8405x; 1.1665x over previous
//
#include <hip/hip_runtime.h>
#include <math.h>

#define B_   128
#define L_   128
#define E_   300
#define P_   50
#define FD_  1000
#define FN_  256
#define H2_  100
#define LAB_ 19

#define KP3 3072
#define KP4 4096
#define KP5 5056
#define PAD_ELEMS 16384

typedef __attribute__((ext_vector_type(8))) short bf16x8;
typedef __attribute__((ext_vector_type(4))) float f32x4;

// round-to-nearest-even f32 -> bf16
__device__ __forceinline__ unsigned short f2bf(float x) {
    unsigned u = __float_as_uint(x);
    u += 0x7FFFu + ((u >> 16) & 1u);
    return (unsigned short)(u >> 16);
}

__device__ __forceinline__ void gld_lds16(const void* g, void* lds_uniform) {
    __builtin_amdgcn_global_load_lds(
        (const __attribute__((address_space(1))) void*)g,
        (__attribute__((address_space(3))) void*)lds_uniform,
        16, 0, 0);
}

#define MEMFENCE asm volatile("" ::: "memory")

// ---- setup: embed build (blocks 0..16383) + weight convert/pad (rest) ----
#define PREP_BLOCKS ((FN_ * (KP3 + KP4 + KP5) + PAD_ELEMS + 255) / 256)
__global__ __launch_bounds__(256) void setup_kernel(
    const int* __restrict__ inputs, const int* __restrict__ p1, const int* __restrict__ p2,
    const float* __restrict__ emb, const float* __restrict__ pos1, const float* __restrict__ pos2,
    unsigned short* __restrict__ embed,
    const float* __restrict__ w3, const float* __restrict__ w4, const float* __restrict__ w5,
    unsigned short* __restrict__ wb3, unsigned short* __restrict__ wb4,
    unsigned short* __restrict__ wb5, unsigned short* __restrict__ pad)
{
    int t = threadIdx.x;
    if (blockIdx.x < B_ * L_) {
        int bi = blockIdx.x;            // b*L + i
        int b = bi >> 7, i = bi & (L_ - 1);
        int tok[3];
#pragma unroll
        for (int j = 0; j < 3; ++j) {
            int pi = i + j;             // padded index 0..L+1
            tok[j] = (pi == 0 || pi == L_ + 1) ? 0 : inputs[b * L_ + pi - 1];
        }
        int pp1 = p1[b * L_ + i], pp2 = p2[b * L_ + i];
        unsigned short* dst = embed + (size_t)bi * FD_;
        for (int d = t; d < FD_; d += 256) {
            float v;
            if (d < 3 * E_) {
                int j = d / E_, dd = d - j * E_;
                v = (i == 0) ? 0.f : emb[(size_t)tok[j] * E_ + dd];
            } else if (d < 3 * E_ + P_) {
                v = pos1[(size_t)pp1 * P_ + (d - 3 * E_)];
            } else {
                v = pos2[(size_t)pp2 * P_ + (d - 3 * E_ - P_)];
            }
            dst[d] = f2bf(v);
        }
    } else {
        const int n3 = FN_ * KP3, n4 = FN_ * KP4, n5 = FN_ * KP5;
        int idx = (blockIdx.x - B_ * L_) * 256 + t;
        if (idx < n3) {
            int f = idx / KP3, c = idx - f * KP3;
            wb3[idx] = (c < 3000) ? f2bf(w3[(size_t)f * 3000 + c]) : (unsigned short)0;
        } else if ((idx -= n3) < n4) {
            int f = idx / KP4, c = idx - f * KP4;
            wb4[idx] = (c < 4000) ? f2bf(w4[(size_t)f * 4000 + c]) : (unsigned short)0;
        } else if ((idx -= n4) < n5) {
            int f = idx / KP5, c = idx - f * KP5;
            wb5[idx] = (c < 5000) ? f2bf(w5[(size_t)f * 5000 + c]) : (unsigned short)0;
        } else if ((idx -= n5) < PAD_ELEMS) {
            pad[idx] = 0;
        }
    }
}

// ---- fused conv-as-GEMM, double-buffered with counted vmcnt + setprio.
// grid = (b, conv, ntile) -- b FASTEST so co-resident blocks share the B panel (L2).
// conv = 2 - blockIdx.y (longest conv group first). 4 waves 2(m)x2(n),
// tile BM=128 x BN=128 x BK=64, XOR-swizzled LDS via pre-swizzled global source.
__global__ __launch_bounds__(256) void conv_mfma_fused(
    const unsigned short* __restrict__ embed,
    const unsigned short* __restrict__ wb3, const unsigned short* __restrict__ wb4,
    const unsigned short* __restrict__ wb5,
    const float* __restrict__ cb3, const float* __restrict__ cb4, const float* __restrict__ cb5,
    float* __restrict__ sf)
{
    __shared__ unsigned short sA[2][128 * 64];   // 2 x 16 KB, chunk-swizzled
    __shared__ unsigned short sB[2][128 * 64];   // 2 x 16 KB
    __shared__ float red[2][128];

    int b    = blockIdx.x;
    int conv = 2 - blockIdx.y;                // 2,1,0 -> k=5,4,3 (longest groups first)
    int n0   = blockIdx.z << 7;               // 0 or 128

    const unsigned short* wbf = (conv == 0) ? wb3 : (conv == 1) ? wb4 : wb5;
    const float* bias         = (conv == 0) ? cb3 : (conv == 1) ? cb4 : cb5;
    int Kpad  = (conv == 0) ? KP3 : (conv == 1) ? KP4 : KP5;
    int M     = 126 - conv;                   // L - k + 1
    int sfcol = conv << 8;                    // conv * FN

    int t = threadIdx.x;
    int w = t >> 6, lane = t & 63;
    int wm = w & 1, wn = w >> 1;
    int l15 = lane & 15, lhi = lane >> 4;

    const char* Abytes = (const char*)(embed + (size_t)b * (L_ * FD_));
    size_t KpadB = (size_t)Kpad * 2;
    const char* Bbytes = (const char*)wbf + (size_t)n0 * KpadB;

    // staging: LDS dest is linear (buf, q*4096 + w*1024 + lane*16);
    // global source chunk pre-swizzled: d = (lane&7) ^ (row&7)  [involution]
    int r_base = (w << 3) + (lane >> 3);
    int dchunk = (lane & 7) ^ (r_base & 7);
    size_t soff = (size_t)dchunk << 4;
    char* sAd = (char*)sA + (w << 10);
    char* sBd = (char*)sB + (w << 10);

    f32x4 acc[4][4] = {};
    int nk = Kpad >> 6;

#define STAGE(BUF, KT)                                                          \
    {                                                                           \
        size_t kb = (size_t)(KT) << 7;                                          \
        _Pragma("unroll")                                                       \
        for (int q = 0; q < 4; ++q) {                                           \
            int row = r_base + (q << 5);                                        \
            gld_lds16(Abytes + (size_t)row * 2000 + kb + soff,                  \
                      sAd + (size_t)(BUF) * 16384 + (q << 12));                 \
            gld_lds16(Bbytes + (size_t)row * KpadB + kb + soff,                 \
                      sBd + (size_t)(BUF) * 16384 + (q << 12));                 \
        }                                                                       \
    }

    STAGE(0, 0);
    int cur = 0;
    for (int kt = 0; kt < nk; ++kt) {
        if (kt + 1 < nk) {
            STAGE(cur ^ 1, kt + 1);
            asm volatile("s_waitcnt vmcnt(8)" ::: "memory");   // cur's 8 loads landed; next's in flight
        } else {
            asm volatile("s_waitcnt vmcnt(0)" ::: "memory");
        }
        MEMFENCE; __builtin_amdgcn_s_barrier(); MEMFENCE;

        const unsigned short* cA = sA[cur];
        const unsigned short* cB = sB[cur];
#pragma unroll
        for (int ks = 0; ks < 2; ++ks) {
            int c = (ks << 2) + lhi;          // logical 16B chunk 0..7
            bf16x8 afr[4], bfr[4];
#pragma unroll
            for (int mf = 0; mf < 4; ++mf) {
                int row = (wm << 6) + (mf << 4) + l15;
                int pc = c ^ (row & 7);
                afr[mf] = *(const bf16x8*)&cA[row * 64 + pc * 8];
            }
#pragma unroll
            for (int nf = 0; nf < 4; ++nf) {
                int fr = (wn << 6) + (nf << 4) + l15;
                int pc = c ^ (fr & 7);
                bfr[nf] = *(const bf16x8*)&cB[fr * 64 + pc * 8];
            }
            __builtin_amdgcn_s_setprio(1);
#pragma unroll
            for (int mf = 0; mf < 4; ++mf)
#pragma unroll
                for (int nf = 0; nf < 4; ++nf)
                    acc[mf][nf] = __builtin_amdgcn_mfma_f32_16x16x32_bf16(
                        afr[mf], bfr[nf], acc[mf][nf], 0, 0, 0);
            __builtin_amdgcn_s_setprio(0);
        }
        MEMFENCE; __builtin_amdgcn_s_barrier(); MEMFENCE;   // all waves done reading cur
        cur ^= 1;
    }
#undef STAGE

    // epilogue: max over valid positions i < M (tanh monotone -> pool before tanh)
#pragma unroll
    for (int nf = 0; nf < 4; ++nf) {
        float bmax = -INFINITY;
#pragma unroll
        for (int mf = 0; mf < 4; ++mf) {
#pragma unroll
            for (int j = 0; j < 4; ++j) {
                int i = (wm << 6) + (mf << 4) + (lhi << 2) + j;
                if (i < M) bmax = fmaxf(bmax, acc[mf][nf][j]);
            }
        }
        bmax = fmaxf(bmax, __shfl_xor(bmax, 16));
        bmax = fmaxf(bmax, __shfl_xor(bmax, 32));
        if (lane < 16) red[wm][(wn << 6) + (nf << 4) + l15] = bmax;
    }
    __syncthreads();
    if (t < 128) {
        float m = fmaxf(red[0][t], red[1][t]);
        sf[(size_t)b * (3 * FN_) + sfcol + n0 + t] = tanhf(m + bias[n0 + t]);
    }
}

// ---- tail: span/lex feats + g + final logits, one block per b ----
__device__ __forceinline__ int tok_at(const int* inputs, int b, int idx) {
    return (idx >= 0 && idx < L_) ? inputs[b * L_ + idx] : 0;
}
__global__ __launch_bounds__(256) void tail_kernel(
    const int* __restrict__ inputs,
    const int* __restrict__ e1s, const int* __restrict__ e1e,
    const int* __restrict__ e2s, const int* __restrict__ e2e,
    const float* __restrict__ emb, const float* __restrict__ sf,
    const float* __restrict__ W1, const float* __restrict__ b1,
    const float* __restrict__ W2, const float* __restrict__ b2,
    float* __restrict__ y)
{
    __shared__ float o_loc[1900];
    __shared__ float sfl[3 * FN_];

    int b = blockIdx.x, t = threadIdx.x;
    int lane = t & 63, w = t >> 6;

    for (int k = t; k < 3 * FN_; k += 256) sfl[k] = sf[(size_t)b * (3 * FN_) + k];

    int s1 = e1s[b], t1 = e1e[b], s2 = e2s[b], t2 = e2e[b];
    float inv1 = 1.f / (float)(t1 - s1 + 1);
    float inv2 = 1.f / (float)(t2 - s2 + 1);
    int ta = tok_at(inputs, b, s1 - 1), tb = tok_at(inputs, b, t1 + 1);
    int tc = tok_at(inputs, b, s2 - 1), td = tok_at(inputs, b, t2 + 1);
    for (int d = t; d < E_; d += 256) {
        float s = 0.f;
        for (int p = s1; p <= t1; ++p) s += emb[(size_t)tok_at(inputs, b, p) * E_ + d];
        o_loc[d] = s * inv1;
        s = 0.f;
        for (int p = s2; p <= t2; ++p) s += emb[(size_t)tok_at(inputs, b, p) * E_ + d];
        o_loc[E_ + d] = s * inv2;
        o_loc[2 * E_ + d] = emb[(size_t)ta * E_ + d];
        o_loc[3 * E_ + d] = emb[(size_t)tb * E_ + d];
        o_loc[4 * E_ + d] = emb[(size_t)tc * E_ + d];
        o_loc[5 * E_ + d] = emb[(size_t)td * E_ + d];
    }
    __syncthreads();

    // g: warp-parallel dots over 768 (coalesced W1 reads)
    for (int h = w; h < H2_; h += 4) {
        const float* wr = W1 + (size_t)h * (3 * FN_);
        float acc = 0.f;
#pragma unroll
        for (int j = 0; j < 12; ++j) acc += sfl[lane + (j << 6)] * wr[lane + (j << 6)];
        for (int off = 32; off; off >>= 1) acc += __shfl_down(acc, off);
        if (lane == 0) o_loc[1800 + h] = tanhf(acc + b1[h]);
    }
    __syncthreads();

    // y = o_loc @ W2.T + b2
    for (int lab = w; lab < LAB_; lab += 4) {
        const float* wr = W2 + (size_t)lab * 1900;
        float acc = 0.f;
        for (int d = lane; d < 1900; d += 64) acc += o_loc[d] * wr[d];
        for (int off = 32; off; off >>= 1) acc += __shfl_down(acc, off);
        if (lane == 0) y[(size_t)b * LAB_ + lab] = acc + b2[lab];
    }
}

extern "C" void kernel_launch(void* const* d_in, const int* in_sizes, int n_in,
                              void* d_out, int out_size, void* d_ws, size_t ws_size,
                              hipStream_t stream) {
    const int*   inputs = (const int*)d_in[0];
    const int*   e1s    = (const int*)d_in[1];
    const int*   e1e    = (const int*)d_in[2];
    const int*   e2s    = (const int*)d_in[3];
    const int*   e2e    = (const int*)d_in[4];
    const int*   p1     = (const int*)d_in[5];
    const int*   p2     = (const int*)d_in[6];
    const float* emb    = (const float*)d_in[7];
    const float* pos1   = (const float*)d_in[8];
    const float* pos2   = (const float*)d_in[9];
    const float* w3     = (const float*)d_in[10];
    const float* cb3    = (const float*)d_in[11];
    const float* w4     = (const float*)d_in[12];
    const float* cb4    = (const float*)d_in[13];
    const float* w5     = (const float*)d_in[14];
    const float* cb5    = (const float*)d_in[15];
    const float* W1     = (const float*)d_in[16];
    const float* b1     = (const float*)d_in[17];
    const float* W2     = (const float*)d_in[18];
    const float* b2     = (const float*)d_in[19];
    float* y = (float*)d_out;

    char* ws = (char*)d_ws;
    size_t off = 0;
    unsigned short* embed = (unsigned short*)(ws + off);
    off += (size_t)B_ * L_ * FD_ * 2 + (size_t)PAD_ELEMS * 2;
    unsigned short* wb3 = (unsigned short*)(ws + off); off += (size_t)FN_ * KP3 * 2;
    unsigned short* wb4 = (unsigned short*)(ws + off); off += (size_t)FN_ * KP4 * 2;
    unsigned short* wb5 = (unsigned short*)(ws + off); off += (size_t)FN_ * KP5 * 2;
    float* sf = (float*)(ws + off); off += (size_t)B_ * 3 * FN_ * 4;

    setup_kernel<<<dim3(B_ * L_ + PREP_BLOCKS), dim3(256), 0, stream>>>(
        inputs, p1, p2, emb, pos1, pos2, embed,
        w3, w4, w5, wb3, wb4, wb5, embed + (size_t)B_ * L_ * FD_);

    conv_mfma_fused<<<dim3(B_, 3, 2), dim3(256), 0, stream>>>(
        embed, wb3, wb4, wb5, cb3, cb4, cb5, sf);

    tail_kernel<<<dim3(B_), dim3(256), 0, stream>>>(
        inputs, e1s, e1e, e2s, e2e, emb, sf, W1, b1, W2, b2, y);
}

// Round 6
// 186.355 us; speedup vs baseline: 8.2425x; 1.2049x over previous
//
#include <hip/hip_runtime.h>
#include <math.h>

#define B_   128
#define L_   128
#define E_   300
#define P_   50
#define FN_  256
#define H2_  100
#define LAB_ 19

typedef unsigned short ushort_t;
typedef __attribute__((ext_vector_type(8))) short bf16x8;
typedef __attribute__((ext_vector_type(4))) short bf16x4;
typedef __attribute__((ext_vector_type(4))) float f32x4;

// ---- folded-K geometry ----
// we part: K = (k+2)*300 padded to x64 ; pos part: K = k*100 padded to x64 ; corr K = 960
#define KW0 1536
#define KW1 1856
#define KW2 2112
#define KPP0 320
#define KPP1 448
#define KPP2 512
#define KC  960

#define WE_STRIDE  40960   // per-b we_flat elems (130 rows x 300 + zero tail)
#define POS_STRIDE 13312   // per-b posflat elems (128 rows x 100 + zero tail)

#define N_WE   (B_ * WE_STRIDE)                      // 5,242,880
#define N_POS  (B_ * POS_STRIDE)                     // 1,703,936
#define N_WFW  (FN_ * (KW0 + KW1 + KW2))             // 1,409,024
#define N_WFP  (FN_ * (KPP0 + KPP1 + KPP2))          // 327,680
#define N_CORR (3 * FN_ * KC)                        // 737,280
#define N_SETUP (N_WE + N_POS + N_WFW + N_WFP + N_CORR)

__device__ __forceinline__ ushort_t f2bf(float x) {
    unsigned u = __float_as_uint(x);
    u += 0x7FFFu + ((u >> 16) & 1u);
    return (ushort_t)(u >> 16);
}

__device__ __forceinline__ void gld_lds16(const void* g, void* lds_uniform) {
    __builtin_amdgcn_global_load_lds(
        (const __attribute__((address_space(1))) void*)g,
        (__attribute__((address_space(3))) void*)lds_uniform,
        16, 0, 0);
}

__device__ __forceinline__ bf16x8 lds_ld8(const ushort_t* p) {
    bf16x4 lo = *(const bf16x4*)p;        // 8B-aligned ds_read_b64
    bf16x4 hi = *(const bf16x4*)(p + 4);
    return __builtin_shufflevector(lo, hi, 0, 1, 2, 3, 4, 5, 6, 7);
}

#define MEMFENCE asm volatile("" ::: "memory")
#define BAR      do { MEMFENCE; __builtin_amdgcn_s_barrier(); MEMFENCE; } while (0)
#define WAITV2   asm volatile("s_waitcnt vmcnt(2)" ::: "memory")
#define WAITV0   asm volatile("s_waitcnt vmcnt(0)" ::: "memory")

// ---- setup: we_flat / posflat / folded+corr weights, one flat-index kernel ----
__global__ __launch_bounds__(256) void setup_kernel(
    const int* __restrict__ inputs, const int* __restrict__ p1, const int* __restrict__ p2,
    const float* __restrict__ emb, const float* __restrict__ pos1, const float* __restrict__ pos2,
    const float* __restrict__ w3, const float* __restrict__ w4, const float* __restrict__ w5,
    ushort_t* __restrict__ we_flat, ushort_t* __restrict__ posflat,
    ushort_t* __restrict__ wfw, ushort_t* __restrict__ wfp, ushort_t* __restrict__ corrw)
{
    int idx = blockIdx.x * 256 + threadIdx.x;

    if (idx < N_WE) {                       // we_flat[b][r*300+c] = emb[tok_pad(b,r)][c]
        int b = idx / WE_STRIDE, rem = idx - b * WE_STRIDE;
        float v = 0.f;
        if (rem < 130 * 300) {
            int r = rem / 300, c = rem - r * 300;
            int tok = (r == 0 || r == 129) ? 0 : inputs[b * L_ + r - 1];
            v = emb[(size_t)tok * 300 + c];
        }
        we_flat[idx] = f2bf(v);
        return;
    }
    idx -= N_WE;
    if (idx < N_POS) {                      // posflat[b][r*100+c] = [pos1|pos2]
        int b = idx / POS_STRIDE, rem = idx - b * POS_STRIDE;
        float v = 0.f;
        if (rem < 128 * 100) {
            int r = rem / 100, c = rem - r * 100;
            v = (c < 50) ? pos1[(size_t)p1[b * L_ + r] * 50 + c]
                         : pos2[(size_t)p2[b * L_ + r] * 50 + (c - 50)];
        }
        posflat[idx] = f2bf(v);
        return;
    }
    idx -= N_POS;
    if (idx < N_WFW) {                      // folded word weights
        int conv, k, kwp, seg;
        if (idx < FN_ * KW0)            { conv = 0; k = 3; kwp = KW0; seg = idx; }
        else if (idx < FN_ * (KW0+KW1)) { conv = 1; k = 4; kwp = KW1; seg = idx - FN_ * KW0; }
        else                            { conv = 2; k = 5; kwp = KW2; seg = idx - FN_ * (KW0+KW1); }
        const float* w = (conv == 0) ? w3 : (conv == 1) ? w4 : w5;
        int f = seg / kwp, kk = seg - f * kwp;
        float s = 0.f;
        if (kk < (k + 2) * 300) {
            int m = kk / 300, c = kk - m * 300;
            int jlo = (m - 2 < 0) ? 0 : m - 2;
            int jhi = (m < k - 1) ? m : k - 1;
            for (int j = jlo; j <= jhi; ++j)
                s += w[(size_t)f * (k * 1000) + j * 1000 + (m - j) * 300 + c];
        }
        wfw[idx] = f2bf(s);
        return;
    }
    idx -= N_WFW;
    if (idx < N_WFP) {                      // pos weights, K = k*100 (+pad)
        int conv, k, kpp, seg;
        if (idx < FN_ * KPP0)              { conv = 0; k = 3; kpp = KPP0; seg = idx; }
        else if (idx < FN_ * (KPP0+KPP1))  { conv = 1; k = 4; kpp = KPP1; seg = idx - FN_ * KPP0; }
        else                               { conv = 2; k = 5; kpp = KPP2; seg = idx - FN_ * (KPP0+KPP1); }
        const float* w = (conv == 0) ? w3 : (conv == 1) ? w4 : w5;
        int f = seg / kpp, kk = seg - f * kpp;
        float v = 0.f;
        if (kk < k * 100) {
            int j = kk / 100, c = kk - j * 100;
            v = w[(size_t)f * (k * 1000) + j * 1000 + 900 + c];
        }
        wfp[idx] = f2bf(v);
        return;
    }
    idx -= N_WFP;
    if (idx < N_CORR) {                     // corr weights: w[f, j=0, 0:900]
        int conv = idx / (FN_ * KC), seg = idx - conv * (FN_ * KC);
        int k = 3 + conv;
        const float* w = (conv == 0) ? w3 : (conv == 1) ? w4 : w5;
        int f = seg / KC, kk = seg - f * KC;
        corrw[idx] = (kk < 900) ? f2bf(w[(size_t)f * (k * 1000) + kk]) : (ushort_t)0;
    }
}

// ---- folded conv: one block per (b, nhalf); A resident in LDS; 3 convs per block ----
__global__ __launch_bounds__(512) void conv_fold(
    const ushort_t* __restrict__ we_flat, const ushort_t* __restrict__ posflat,
    const ushort_t* __restrict__ wfw, const ushort_t* __restrict__ wfp,
    const ushort_t* __restrict__ corrw,
    const float* __restrict__ cb3, const float* __restrict__ cb4, const float* __restrict__ cb5,
    float* __restrict__ sf)
{
    __shared__ ushort_t we_lds[WE_STRIDE];    // 81,920 B, stride-300 unfold source
    __shared__ ushort_t pos_lds[POS_STRIDE];  // 26,624 B, stride-100 unfold source
    __shared__ ushort_t sB[2][8192];          // 2 x 16 KB weight tiles (chunk-swizzled)
    __shared__ float red[2][128];

    int b  = blockIdx.x;
    int n0 = blockIdx.y << 7;

    int t = threadIdx.x;
    int w = t >> 6, lane = t & 63;
    int wm = w & 1, wn = w >> 1;              // 2(m) x 4(n) waves
    int l15 = lane & 15, lhi = lane >> 4;

    // ---- load A (whole b-slice) to LDS, linear ----
    const char* wesrc = (const char*)(we_flat + (size_t)b * WE_STRIDE);
#pragma unroll
    for (int q = 0; q < 10; ++q) {            // 5120 chunks
        int ci = (q << 9) + t;
        gld_lds16(wesrc + ((size_t)ci << 4), (char*)we_lds + (ci << 4));
    }
    const char* pssrc = (const char*)(posflat + (size_t)b * POS_STRIDE);
#pragma unroll
    for (int q = 0; q < 4; ++q) {             // 1664 chunks (last round: waves 0,1 only)
        int ci = (q << 9) + t;
        if (ci < 1664)
            gld_lds16(pssrc + ((size_t)ci << 4), (char*)pos_lds + (ci << 4));
    }

    // B staging: linear LDS dest, pre-swizzled global source chunk (involution)
#define STAGEB(BUF, BASE, KB, KT)                                               \
    {                                                                           \
        _Pragma("unroll")                                                       \
        for (int u = 0; u < 2; ++u) {                                           \
            int ci = (u << 9) + t;                                              \
            int fr = ci >> 3, cin = ci & 7;                                     \
            int sc = cin ^ (fr & 7);                                            \
            gld_lds16((BASE) + (size_t)fr * (KB) + ((size_t)(KT) << 7) + (sc << 4), \
                      (char*)sB + ((BUF) << 14) + (ci << 4));                   \
        }                                                                       \
    }

    const int ntw_a[3] = {KW0 / 64, KW1 / 64, KW2 / 64};
    const int ntp_a[3] = {KPP0 / 64, KPP1 / 64, KPP2 / 64};
    const size_t owfw_a[3] = {0, (size_t)FN_ * KW0, (size_t)FN_ * (KW0 + KW1)};
    const size_t owfp_a[3] = {0, (size_t)FN_ * KPP0, (size_t)FN_ * (KPP0 + KPP1)};

    // per-row LDS base pointers for A fragments
    const ushort_t* weRow[4];
    const ushort_t* posRow[4];
#pragma unroll
    for (int mf = 0; mf < 4; ++mf) {
        int row = (wm << 6) + (mf << 4) + l15;
        weRow[mf]  = we_lds  + row * 300;
        posRow[mf] = pos_lds + row * 100;
    }

#pragma unroll 1
    for (int conv = 0; conv < 3; ++conv) {
        int ntw = ntw_a[conv], ntp = ntp_a[conv];
        size_t kbw = (size_t)ntw * 128, kbp = (size_t)ntp * 128;   // row strides, bytes
        const char* Bw = (const char*)(wfw + owfw_a[conv] + (size_t)n0 * (ntw * 64));
        const char* Bp = (const char*)(wfp + owfp_a[conv] + (size_t)n0 * (ntp * 64));
        const char* Bc = (const char*)(corrw + (size_t)conv * (FN_ * KC) + (size_t)n0 * KC);

        f32x4 acc[4][2] = {};
        f32x4 accc[2] = {};
        int cur;

        // ---- corr mini-GEMM: broadcast A = we_lds[0:900] (first iter also drains A loads)
        STAGEB(0, Bc, (size_t)(KC * 2), 0);
        cur = 0;
        for (int kt = 0; kt < KC / 64; ++kt) {
            if (kt + 1 < KC / 64) { STAGEB(cur ^ 1, Bc, (size_t)(KC * 2), kt + 1); WAITV2; }
            else WAITV0;
            BAR;
#pragma unroll
            for (int ks = 0; ks < 2; ++ks) {
                int kk = (kt << 6) + (ks << 5);
                bf16x8 af = lds_ld8(we_lds + kk + (lhi << 3));   // uniform addr: LDS broadcast
#pragma unroll
                for (int nf = 0; nf < 2; ++nf) {
                    int fr = (wn << 5) + (nf << 4) + l15;
                    int pc = ((ks << 2) + lhi) ^ (fr & 7);
                    bf16x8 bf = *(const bf16x8*)&sB[cur][fr * 64 + pc * 8];
                    accc[nf] = __builtin_amdgcn_mfma_f32_16x16x32_bf16(af, bf, accc[nf], 0, 0, 0);
                }
            }
            BAR; cur ^= 1;
        }

        // ---- word part: A[i,kk] = we_lds[i*300 + kk]
        STAGEB(0, Bw, kbw, 0);
        cur = 0;
        for (int kt = 0; kt < ntw; ++kt) {
            if (kt + 1 < ntw) { STAGEB(cur ^ 1, Bw, kbw, kt + 1); WAITV2; }
            else WAITV0;
            BAR;
#pragma unroll
            for (int ks = 0; ks < 2; ++ks) {
                int kk = (kt << 6) + (ks << 5) + (lhi << 3);
                bf16x8 afr[4], bfr[2];
#pragma unroll
                for (int mf = 0; mf < 4; ++mf) afr[mf] = lds_ld8(weRow[mf] + kk);
#pragma unroll
                for (int nf = 0; nf < 2; ++nf) {
                    int fr = (wn << 5) + (nf << 4) + l15;
                    int pc = ((ks << 2) + lhi) ^ (fr & 7);
                    bfr[nf] = *(const bf16x8*)&sB[cur][fr * 64 + pc * 8];
                }
                __builtin_amdgcn_s_setprio(1);
#pragma unroll
                for (int mf = 0; mf < 4; ++mf)
#pragma unroll
                    for (int nf = 0; nf < 2; ++nf)
                        acc[mf][nf] = __builtin_amdgcn_mfma_f32_16x16x32_bf16(
                            afr[mf], bfr[nf], acc[mf][nf], 0, 0, 0);
                __builtin_amdgcn_s_setprio(0);
            }
            BAR; cur ^= 1;
        }

        // ---- pos part: A[i,kk] = pos_lds[i*100 + kk]
        STAGEB(0, Bp, kbp, 0);
        cur = 0;
        for (int kt = 0; kt < ntp; ++kt) {
            if (kt + 1 < ntp) { STAGEB(cur ^ 1, Bp, kbp, kt + 1); WAITV2; }
            else WAITV0;
            BAR;
#pragma unroll
            for (int ks = 0; ks < 2; ++ks) {
                int kk = (kt << 6) + (ks << 5) + (lhi << 3);
                bf16x8 afr[4], bfr[2];
#pragma unroll
                for (int mf = 0; mf < 4; ++mf) afr[mf] = lds_ld8(posRow[mf] + kk);
#pragma unroll
                for (int nf = 0; nf < 2; ++nf) {
                    int fr = (wn << 5) + (nf << 4) + l15;
                    int pc = ((ks << 2) + lhi) ^ (fr & 7);
                    bfr[nf] = *(const bf16x8*)&sB[cur][fr * 64 + pc * 8];
                }
                __builtin_amdgcn_s_setprio(1);
#pragma unroll
                for (int mf = 0; mf < 4; ++mf)
#pragma unroll
                    for (int nf = 0; nf < 2; ++nf)
                        acc[mf][nf] = __builtin_amdgcn_mfma_f32_16x16x32_bf16(
                            afr[mf], bfr[nf], acc[mf][nf], 0, 0, 0);
                __builtin_amdgcn_s_setprio(0);
            }
            BAR; cur ^= 1;
        }

        // ---- epilogue: i=0 correction, masked max-pool, bias+tanh, store
        float cval0 = accc[0][0], cval1 = accc[1][0];
        int M = 126 - conv;
#pragma unroll
        for (int nf = 0; nf < 2; ++nf) {
            float bmax = -INFINITY;
#pragma unroll
            for (int mf = 0; mf < 4; ++mf) {
#pragma unroll
                for (int j = 0; j < 4; ++j) {
                    int i = (wm << 6) + (mf << 4) + (lhi << 2) + j;
                    float v = acc[mf][nf][j];
                    if (wm == 0 && mf == 0 && lhi == 0 && j == 0)
                        v -= (nf ? cval1 : cval0);        // WF row-0 zeroing fix
                    if (i < M) bmax = fmaxf(bmax, v);
                }
            }
            bmax = fmaxf(bmax, __shfl_xor(bmax, 16));
            bmax = fmaxf(bmax, __shfl_xor(bmax, 32));
            if (lane < 16) red[wm][(wn << 5) + (nf << 4) + l15] = bmax;
        }
        __syncthreads();
        if (t < 128) {
            float m = fmaxf(red[0][t], red[1][t]);
            const float* bias = (conv == 0) ? cb3 : (conv == 1) ? cb4 : cb5;
            sf[(size_t)b * (3 * FN_) + (conv << 8) + n0 + t] = tanhf(m + bias[n0 + t]);
        }
        __syncthreads();
    }
#undef STAGEB
}

// ---- tail: span/lex feats + g + final logits, one block per b ----
__device__ __forceinline__ int tok_at(const int* inputs, int b, int idx) {
    return (idx >= 0 && idx < L_) ? inputs[b * L_ + idx] : 0;
}
__global__ __launch_bounds__(256) void tail_kernel(
    const int* __restrict__ inputs,
    const int* __restrict__ e1s, const int* __restrict__ e1e,
    const int* __restrict__ e2s, const int* __restrict__ e2e,
    const float* __restrict__ emb, const float* __restrict__ sf,
    const float* __restrict__ W1, const float* __restrict__ b1,
    const float* __restrict__ W2, const float* __restrict__ b2,
    float* __restrict__ y)
{
    __shared__ float o_loc[1900];
    __shared__ float sfl[3 * FN_];

    int b = blockIdx.x, t = threadIdx.x;
    int lane = t & 63, w = t >> 6;

    for (int k = t; k < 3 * FN_; k += 256) sfl[k] = sf[(size_t)b * (3 * FN_) + k];

    int s1 = e1s[b], t1 = e1e[b], s2 = e2s[b], t2 = e2e[b];
    float inv1 = 1.f / (float)(t1 - s1 + 1);
    float inv2 = 1.f / (float)(t2 - s2 + 1);
    int ta = tok_at(inputs, b, s1 - 1), tb = tok_at(inputs, b, t1 + 1);
    int tc = tok_at(inputs, b, s2 - 1), td = tok_at(inputs, b, t2 + 1);
    for (int d = t; d < E_; d += 256) {
        float s = 0.f;
        for (int p = s1; p <= t1; ++p) s += emb[(size_t)tok_at(inputs, b, p) * E_ + d];
        o_loc[d] = s * inv1;
        s = 0.f;
        for (int p = s2; p <= t2; ++p) s += emb[(size_t)tok_at(inputs, b, p) * E_ + d];
        o_loc[E_ + d] = s * inv2;
        o_loc[2 * E_ + d] = emb[(size_t)ta * E_ + d];
        o_loc[3 * E_ + d] = emb[(size_t)tb * E_ + d];
        o_loc[4 * E_ + d] = emb[(size_t)tc * E_ + d];
        o_loc[5 * E_ + d] = emb[(size_t)td * E_ + d];
    }
    __syncthreads();

    for (int h = w; h < H2_; h += 4) {
        const float* wr = W1 + (size_t)h * (3 * FN_);
        float acc = 0.f;
#pragma unroll
        for (int j = 0; j < 12; ++j) acc += sfl[lane + (j << 6)] * wr[lane + (j << 6)];
        for (int off = 32; off; off >>= 1) acc += __shfl_down(acc, off);
        if (lane == 0) o_loc[1800 + h] = tanhf(acc + b1[h]);
    }
    __syncthreads();

    for (int lab = w; lab < LAB_; lab += 4) {
        const float* wr = W2 + (size_t)lab * 1900;
        float acc = 0.f;
        for (int d = lane; d < 1900; d += 64) acc += o_loc[d] * wr[d];
        for (int off = 32; off; off >>= 1) acc += __shfl_down(acc, off);
        if (lane == 0) y[(size_t)b * LAB_ + lab] = acc + b2[lab];
    }
}

extern "C" void kernel_launch(void* const* d_in, const int* in_sizes, int n_in,
                              void* d_out, int out_size, void* d_ws, size_t ws_size,
                              hipStream_t stream) {
    const int*   inputs = (const int*)d_in[0];
    const int*   e1s    = (const int*)d_in[1];
    const int*   e1e    = (const int*)d_in[2];
    const int*   e2s    = (const int*)d_in[3];
    const int*   e2e    = (const int*)d_in[4];
    const int*   p1     = (const int*)d_in[5];
    const int*   p2     = (const int*)d_in[6];
    const float* emb    = (const float*)d_in[7];
    const float* pos1   = (const float*)d_in[8];
    const float* pos2   = (const float*)d_in[9];
    const float* w3     = (const float*)d_in[10];
    const float* cb3    = (const float*)d_in[11];
    const float* w4     = (const float*)d_in[12];
    const float* cb4    = (const float*)d_in[13];
    const float* w5     = (const float*)d_in[14];
    const float* cb5    = (const float*)d_in[15];
    const float* W1     = (const float*)d_in[16];
    const float* b1     = (const float*)d_in[17];
    const float* W2     = (const float*)d_in[18];
    const float* b2     = (const float*)d_in[19];
    float* y = (float*)d_out;

    char* ws = (char*)d_ws;
    size_t off = 0;
    ushort_t* we_flat = (ushort_t*)(ws + off); off += (size_t)N_WE * 2;
    ushort_t* posflat = (ushort_t*)(ws + off); off += (size_t)N_POS * 2;
    ushort_t* wfw     = (ushort_t*)(ws + off); off += (size_t)N_WFW * 2;
    ushort_t* wfp     = (ushort_t*)(ws + off); off += (size_t)N_WFP * 2;
    ushort_t* corrw   = (ushort_t*)(ws + off); off += (size_t)N_CORR * 2;
    float*    sf      = (float*)(ws + off);    off += (size_t)B_ * 3 * FN_ * 4;

    setup_kernel<<<dim3(N_SETUP / 256), dim3(256), 0, stream>>>(
        inputs, p1, p2, emb, pos1, pos2, w3, w4, w5,
        we_flat, posflat, wfw, wfp, corrw);

    conv_fold<<<dim3(B_, 2), dim3(512), 0, stream>>>(
        we_flat, posflat, wfw, wfp, corrw, cb3, cb4, cb5, sf);

    tail_kernel<<<dim3(B_), dim3(256), 0, stream>>>(
        inputs, e1s, e1e, e2s, e2e, emb, sf, W1, b1, W2, b2, y);
}